// Round 8
// baseline (47.833 us; speedup 1.0000x reference)
//
#include <hip/hip_runtime.h>
#include <math.h>

#define NPATHS   1024
#define CANVAS_H 224
#define CANVAS_W 224
#define NPIX     (CANVAS_H * CANVAS_W)   // 50176
#define NSAMP    49          // linspace(0,1,50)[:-1] -> t_i = i/49
#define K2EXP    72.134752f  // 50/ln(2): sigmoid(50*(r-d)) = 1/(1+exp2((d-r)*K2EXP))

#define NWAVES   8
#define PPW      (NPATHS / NWAVES)       // 128 paths per wave

// Per-path record (2x float4): [cx, cy, c2=-K2EXP*r, alpha | cr*a, cg*a, cb*a, pad]
// No cull: sigmoid saturates exactly (e=exp2(arg) huge -> q=0, om=1), max
// arg = sqrt(2)*72.1 ~ 102 -> 2^102 finite, no clamp needed.

typedef __attribute__((ext_vector_type(16))) int   i16x16;
typedef __attribute__((ext_vector_type(2)))  float f32x2;

__device__ __forceinline__ float sf(int v) { return __int_as_float(v); }

// One thread per (path, segment): 4096 threads; 4-lane shfl_xor reduce.
__global__ __launch_bounds__(256) void path_setup_kernel(
    const float* __restrict__ cps,     // (P, 4, 4, 2)
    const float* __restrict__ colors,  // (P, 4)
    float* __restrict__ pd)            // (P, 8)
{
    const int tid = blockIdx.x * 256 + threadIdx.x;
    const int p = tid >> 2;
    const int s = tid & 3;

    const float4* cp4 = reinterpret_cast<const float4*>(cps);
    float4 a = cp4[p * 8 + s * 2];       // x0,y0,x1,y1
    float4 b = cp4[p * 8 + s * 2 + 1];   // x2,y2,x3,y3

    float sx = 0.0f, sy = 0.0f;
    for (int i = 0; i < NSAMP; ++i) {
        float t  = (float)i * (1.0f / 49.0f);
        float mt = 1.0f - t;
        float b0 = mt * mt * mt;
        float b1 = 3.0f * mt * mt * t;
        float b2 = 3.0f * mt * t * t;
        float b3 = t * t * t;
        sx += b0 * a.x + b1 * a.z + b2 * b.x + b3 * b.z;
        sy += b0 * a.y + b1 * a.w + b2 * b.y + b3 * b.w;
    }
    sx += __shfl_xor(sx, 1); sx += __shfl_xor(sx, 2);
    sy += __shfl_xor(sy, 1); sy += __shfl_xor(sy, 2);
    const float inv_n = 1.0f / 196.0f;
    float cx = sx * inv_n;
    float cy = sy * inv_n;

    float sr = 0.0f;
    for (int i = 0; i < NSAMP; ++i) {
        float t  = (float)i * (1.0f / 49.0f);
        float mt = 1.0f - t;
        float b0 = mt * mt * mt;
        float b1 = 3.0f * mt * mt * t;
        float b2 = 3.0f * mt * t * t;
        float b3 = t * t * t;
        float ptx = b0 * a.x + b1 * a.z + b2 * b.x + b3 * b.z;
        float pty = b0 * a.y + b1 * a.w + b2 * b.y + b3 * b.w;
        float dx = ptx - cx;
        float dy = pty - cy;
        sr += sqrtf(dx * dx + dy * dy);
    }
    sr += __shfl_xor(sr, 1); sr += __shfl_xor(sr, 2);
    float r = sr * inv_n;

    if (s == 0) {
        float4 col = reinterpret_cast<const float4*>(colors)[p];
        float4* o = reinterpret_cast<float4*>(pd) + (size_t)p * 2;
        o[0] = make_float4(cx, cy, -K2EXP * r, col.w);
        o[1] = make_float4(col.x * col.w, col.y * col.w, col.z * col.w, 0.0f);
    }
}

// One block = one 8x8 pixel tile; 8 waves, wave w handles paths [128w,128w+128)
// for all 64 pixels (lane = pixel). Path records stream in via ping-pong
// s_load_dwordx16 (64B = 2 records, one outstanding prefetch hidden under the
// previous 2-path body). Inner loop is STRAIGHT-LINE: no cull branch, no exec
// mask churn — 12 VALU + 3 trans per path. Ordered cross-wave combine in LDS.
__global__ __launch_bounds__(512) void render_kernel(
    const float* __restrict__ pd,   // (P, 8)
    float* __restrict__ out)        // (3, H, W)
{
    __shared__ float4 xch[NWAVES * 64];   // 8 KB

    const int wave = __builtin_amdgcn_readfirstlane((int)(threadIdx.x >> 6));
    const int lane = threadIdx.x & 63;
    const int lx = lane & 7;
    const int ly = lane >> 3;
    const int xx = blockIdx.x * 8 + lx;    // 28 * 8 = 224
    const int yy = blockIdx.y * 8 + ly;

    f32x2 pxy;
    pxy.x = (float)xx * (1.0f / 223.0f);
    pxy.y = (float)yy * (1.0f / 223.0f);

    const float* wptr = pd + (size_t)wave * (PPW * 8);   // wave-uniform

    float T = 1.0f, Ab = 0.0f;
    f32x2 ra; ra.x = 0.0f; ra.y = 0.0f;   // (Ar, Ag)

#define BODY(blk, j)                                                       \
    {                                                                      \
        const int o = (j) * 8;                                             \
        f32x2 cxy;                                                         \
        cxy.x = sf(blk[o + 0]);                                            \
        cxy.y = sf(blk[o + 1]);                                            \
        float c2  = sf(blk[o + 2]);                                        \
        float al  = sf(blk[o + 3]);                                        \
        f32x2 dxy = pxy - cxy;                                             \
        float d2  = __builtin_fmaf(dxy.x, dxy.x, dxy.y * dxy.y);           \
        float dist = __builtin_amdgcn_sqrtf(d2);                           \
        float e = __builtin_amdgcn_exp2f(__builtin_fmaf(dist, K2EXP, c2)); \
        float q = __builtin_amdgcn_rcpf(1.0f + e);                         \
        float om = __builtin_fmaf(-al, q, 1.0f);                           \
        f32x2 crg;                                                         \
        crg.x = sf(blk[o + 4]);                                            \
        crg.y = sf(blk[o + 5]);                                            \
        float cba = sf(blk[o + 6]);                                        \
        f32x2 om2; om2.x = om; om2.y = om;                                 \
        f32x2 q2;  q2.x = q;   q2.y = q;                                   \
        ra = ra * om2 + crg * q2;                                          \
        T  = T * om;                                                       \
        Ab = __builtin_fmaf(Ab, om, cba * q);                              \
    }

    i16x16 A, B;
    // Prologue: load block 0 (paths 0-1), wait.
    asm volatile("s_load_dwordx16 %0, %1, 0x0" : "=s"(A) : "s"(wptr));
    asm volatile("s_waitcnt lgkmcnt(0)" : "+s"(A));

    // 32 iterations x 4 paths (2 ping-pong 64B blocks per iteration).
    for (int i = 0; i < PPW / 4; ++i) {
        // Prefetch odd block (paths 4i+2, 4i+3) while computing A.
        asm volatile("s_load_dwordx16 %0, %1, 0x0"
                     : "=s"(B) : "s"(wptr + (size_t)(2 * i + 1) * 16));
        BODY(A, 0)
        BODY(A, 1)
        asm volatile("s_waitcnt lgkmcnt(0)" : "+s"(B));
        // Prefetch next even block while computing B.
        if (i < PPW / 4 - 1)
            asm volatile("s_load_dwordx16 %0, %1, 0x0"
                         : "=s"(A) : "s"(wptr + (size_t)(2 * i + 2) * 16));
        BODY(B, 0)
        BODY(B, 1)
        asm volatile("s_waitcnt lgkmcnt(0)" : "+s"(A));
    }
#undef BODY

    xch[wave * 64 + lane] = make_float4(T, ra.x, ra.y, Ab);
    __syncthreads();

    if (wave == 0) {
        float R = 1.0f, G = 1.0f, B2 = 1.0f;
#pragma unroll
        for (int w = 0; w < NWAVES; ++w) {
            float4 c = xch[w * 64 + lane];
            R  = __builtin_fmaf(R,  c.x, c.y);
            G  = __builtin_fmaf(G,  c.x, c.z);
            B2 = __builtin_fmaf(B2, c.x, c.w);
        }
        const int pix = yy * CANVAS_W + xx;
        out[pix]            = R;
        out[NPIX + pix]     = G;
        out[2 * NPIX + pix] = B2;
    }
}

extern "C" void kernel_launch(void* const* d_in, const int* in_sizes, int n_in,
                              void* d_out, int out_size, void* d_ws, size_t ws_size,
                              hipStream_t stream) {
    const float* cps    = (const float*)d_in[0];
    const float* colors = (const float*)d_in[1];
    float* out = (float*)d_out;
    float* pd  = (float*)d_ws;   // 32 KB

    path_setup_kernel<<<(NPATHS * 4) / 256, 256, 0, stream>>>(cps, colors, pd);

    dim3 grid(CANVAS_W / 8, CANVAS_H / 8);   // 28 x 28 = 784 blocks
    render_kernel<<<grid, 512, 0, stream>>>(pd, out);
}

// Round 9
// 44.973 us; speedup vs baseline: 1.0636x; 1.0636x over previous
//
#include <hip/hip_runtime.h>
#include <math.h>

#define NPATHS   1024
#define CANVAS_H 224
#define CANVAS_W 224
#define NPIX     (CANVAS_H * CANVAS_W)   // 50176
#define NSAMP    49          // linspace(0,1,50)[:-1] -> t_i = i/49
#define K2EXP    72.134752f  // 50/ln(2): sigmoid(50*(r-d)) = 1/(1+exp2((d-r)*K2EXP))

#define NWAVES   8
#define PPW      (NPATHS / NWAVES)       // 128 paths per wave

// Per-path record (2x float4): [cx, cy, c2=-K2EXP*r, alpha | cr*a, cg*a, cb*a, pad]
// No cull: sigmoid saturates exactly (e huge -> q=0, om=1), max arg ~ 102 -> finite.

typedef __attribute__((ext_vector_type(16))) int   i16x16;
typedef __attribute__((ext_vector_type(2)))  float f32x2;

__device__ __forceinline__ float sf(int v) { return __int_as_float(v); }

// One thread per (path, segment): 4096 threads; 4-lane shfl_xor reduce.
__global__ __launch_bounds__(256) void path_setup_kernel(
    const float* __restrict__ cps,     // (P, 4, 4, 2)
    const float* __restrict__ colors,  // (P, 4)
    float* __restrict__ pd)            // (P, 8)
{
    const int tid = blockIdx.x * 256 + threadIdx.x;
    const int p = tid >> 2;
    const int s = tid & 3;

    const float4* cp4 = reinterpret_cast<const float4*>(cps);
    float4 a = cp4[p * 8 + s * 2];       // x0,y0,x1,y1
    float4 b = cp4[p * 8 + s * 2 + 1];   // x2,y2,x3,y3

    float sx = 0.0f, sy = 0.0f;
    for (int i = 0; i < NSAMP; ++i) {
        float t  = (float)i * (1.0f / 49.0f);
        float mt = 1.0f - t;
        float b0 = mt * mt * mt;
        float b1 = 3.0f * mt * mt * t;
        float b2 = 3.0f * mt * t * t;
        float b3 = t * t * t;
        sx += b0 * a.x + b1 * a.z + b2 * b.x + b3 * b.z;
        sy += b0 * a.y + b1 * a.w + b2 * b.y + b3 * b.w;
    }
    sx += __shfl_xor(sx, 1); sx += __shfl_xor(sx, 2);
    sy += __shfl_xor(sy, 1); sy += __shfl_xor(sy, 2);
    const float inv_n = 1.0f / 196.0f;
    float cx = sx * inv_n;
    float cy = sy * inv_n;

    float sr = 0.0f;
    for (int i = 0; i < NSAMP; ++i) {
        float t  = (float)i * (1.0f / 49.0f);
        float mt = 1.0f - t;
        float b0 = mt * mt * mt;
        float b1 = 3.0f * mt * mt * t;
        float b2 = 3.0f * mt * t * t;
        float b3 = t * t * t;
        float ptx = b0 * a.x + b1 * a.z + b2 * b.x + b3 * b.z;
        float pty = b0 * a.y + b1 * a.w + b2 * b.y + b3 * b.w;
        float dx = ptx - cx;
        float dy = pty - cy;
        sr += sqrtf(dx * dx + dy * dy);
    }
    sr += __shfl_xor(sr, 1); sr += __shfl_xor(sr, 2);
    float r = sr * inv_n;

    if (s == 0) {
        float4 col = reinterpret_cast<const float4*>(colors)[p];
        float4* o = reinterpret_cast<float4*>(pd) + (size_t)p * 2;
        o[0] = make_float4(cx, cy, -K2EXP * r, col.w);
        o[1] = make_float4(col.x * col.w, col.y * col.w, col.z * col.w, 0.0f);
    }
}

// One block = one 16x8 pixel tile; 8 waves; wave w handles paths [128w,128w+128)
// for all 128 pixels (2 px/lane: lanes are a 16x4 grid, sub-pixels at rows
// +0 and +4). Path records stream via double-buffered PAIRS of
// s_load_dwordx16 (4 paths per buffer): one lgkmcnt(0) wait per ~336 cyc of
// straight-line compute, so SMEM latency hides. dx^2 and all per-path operand
// unpack shared between the lane's two pixels. Ordered cross-wave combine in LDS.
__global__ __launch_bounds__(512) void render_kernel(
    const float* __restrict__ pd,   // (P, 8)
    float* __restrict__ out)        // (3, H, W)
{
    __shared__ float4 xch[NWAVES * 2 * 64];   // 16 KB

    const int wave = __builtin_amdgcn_readfirstlane((int)(threadIdx.x >> 6));
    const int lane = threadIdx.x & 63;
    const int lx = lane & 15;          // 0..15
    const int lq = lane >> 4;          // 0..3
    const int xx  = blockIdx.x * 16 + lx;    // 14 * 16 = 224
    const int yy0 = blockIdx.y * 8 + lq;     // 28 * 8  = 224
    const float px  = (float)xx  * (1.0f / 223.0f);
    const float py0 = (float)yy0 * (1.0f / 223.0f);
    const float py1 = (float)(yy0 + 4) * (1.0f / 223.0f);

    const float* wptr = pd + (size_t)wave * (PPW * 8);   // wave-uniform

    float T0 = 1.0f, Ab0 = 0.0f, T1 = 1.0f, Ab1 = 0.0f;
    f32x2 ra0; ra0.x = 0.0f; ra0.y = 0.0f;   // (Ar, Ag) for sub-pixel 0
    f32x2 ra1; ra1.x = 0.0f; ra1.y = 0.0f;   // (Ar, Ag) for sub-pixel 1

#define PBODY(blk, o)                                                        \
    {                                                                        \
        float cx  = sf(blk[(o) + 0]);                                        \
        float cy  = sf(blk[(o) + 1]);                                        \
        float c2  = sf(blk[(o) + 2]);                                        \
        float al  = sf(blk[(o) + 3]);                                        \
        float crx = sf(blk[(o) + 4]);                                        \
        float cgy = sf(blk[(o) + 5]);                                        \
        float cba = sf(blk[(o) + 6]);                                        \
        float dx  = px - cx;                                                 \
        float dx2 = dx * dx;                                                 \
        float dy0 = py0 - cy;                                                \
        float dy1 = py1 - cy;                                                \
        float d20 = __builtin_fmaf(dy0, dy0, dx2);                           \
        float d21 = __builtin_fmaf(dy1, dy1, dx2);                           \
        float s0 = __builtin_amdgcn_sqrtf(d20);                              \
        float s1 = __builtin_amdgcn_sqrtf(d21);                              \
        float e0 = __builtin_amdgcn_exp2f(__builtin_fmaf(s0, K2EXP, c2));    \
        float e1 = __builtin_amdgcn_exp2f(__builtin_fmaf(s1, K2EXP, c2));    \
        float q0 = __builtin_amdgcn_rcpf(1.0f + e0);                         \
        float q1 = __builtin_amdgcn_rcpf(1.0f + e1);                         \
        float om0 = __builtin_fmaf(-al, q0, 1.0f);                           \
        float om1 = __builtin_fmaf(-al, q1, 1.0f);                           \
        f32x2 crg; crg.x = crx; crg.y = cgy;                                 \
        f32x2 om0v; om0v.x = om0; om0v.y = om0;                              \
        f32x2 om1v; om1v.x = om1; om1v.y = om1;                              \
        f32x2 q0v;  q0v.x = q0;  q0v.y = q0;                                 \
        f32x2 q1v;  q1v.x = q1;  q1v.y = q1;                                 \
        ra0 = ra0 * om0v + crg * q0v;                                        \
        ra1 = ra1 * om1v + crg * q1v;                                        \
        T0 *= om0;                                                           \
        T1 *= om1;                                                           \
        Ab0 = __builtin_fmaf(Ab0, om0, cba * q0);                            \
        Ab1 = __builtin_fmaf(Ab1, om1, cba * q1);                            \
    }

    i16x16 A0, A1, B0, B1;
    // Prologue: load group 0 (paths 0-3 = 128B), wait.
    asm volatile("s_load_dwordx16 %0, %1, 0x0" : "=s"(A0) : "s"(wptr));
    asm volatile("s_load_dwordx16 %0, %1, 0x0" : "=s"(A1) : "s"(wptr + 16));
    asm volatile("s_waitcnt lgkmcnt(0)" : "+s"(A0), "+s"(A1));

    // 16 iterations x 8 paths (two 4-path groups per iteration, ping-pong).
    for (int i = 0; i < PPW / 8; ++i) {
        const float* gB = wptr + (size_t)(i * 64 + 32);
        asm volatile("s_load_dwordx16 %0, %1, 0x0" : "=s"(B0) : "s"(gB));
        asm volatile("s_load_dwordx16 %0, %1, 0x0" : "=s"(B1) : "s"(gB + 16));
        PBODY(A0, 0) PBODY(A0, 8) PBODY(A1, 0) PBODY(A1, 8)
        asm volatile("s_waitcnt lgkmcnt(0)" : "+s"(B0), "+s"(B1));
        if (i < PPW / 8 - 1) {
            const float* gA = wptr + (size_t)(i * 64 + 64);
            asm volatile("s_load_dwordx16 %0, %1, 0x0" : "=s"(A0) : "s"(gA));
            asm volatile("s_load_dwordx16 %0, %1, 0x0" : "=s"(A1) : "s"(gA + 16));
        }
        PBODY(B0, 0) PBODY(B0, 8) PBODY(B1, 0) PBODY(B1, 8)
        asm volatile("s_waitcnt lgkmcnt(0)" : "+s"(A0), "+s"(A1));
    }
#undef PBODY

    xch[wave * 128 + lane]      = make_float4(T0, ra0.x, ra0.y, Ab0);
    xch[wave * 128 + 64 + lane] = make_float4(T1, ra1.x, ra1.y, Ab1);
    __syncthreads();

    if (wave == 0) {
#pragma unroll
        for (int sub = 0; sub < 2; ++sub) {
            float R = 1.0f, G = 1.0f, Bb = 1.0f;
#pragma unroll
            for (int w = 0; w < NWAVES; ++w) {
                float4 c = xch[w * 128 + sub * 64 + lane];
                R  = __builtin_fmaf(R,  c.x, c.y);
                G  = __builtin_fmaf(G,  c.x, c.z);
                Bb = __builtin_fmaf(Bb, c.x, c.w);
            }
            const int pix = (yy0 + sub * 4) * CANVAS_W + xx;
            out[pix]            = R;
            out[NPIX + pix]     = G;
            out[2 * NPIX + pix] = Bb;
        }
    }
}

extern "C" void kernel_launch(void* const* d_in, const int* in_sizes, int n_in,
                              void* d_out, int out_size, void* d_ws, size_t ws_size,
                              hipStream_t stream) {
    const float* cps    = (const float*)d_in[0];
    const float* colors = (const float*)d_in[1];
    float* out = (float*)d_out;
    float* pd  = (float*)d_ws;   // 32 KB

    path_setup_kernel<<<(NPATHS * 4) / 256, 256, 0, stream>>>(cps, colors, pd);

    dim3 grid(CANVAS_W / 16, CANVAS_H / 8);   // 14 x 28 = 392 blocks
    render_kernel<<<grid, 512, 0, stream>>>(pd, out);
}

// Round 10
// 44.383 us; speedup vs baseline: 1.0777x; 1.0133x over previous
//
#include <hip/hip_runtime.h>
#include <math.h>

#define NPATHS   1024
#define CANVAS_H 224
#define CANVAS_W 224
#define NPIX     (CANVAS_H * CANVAS_W)   // 50176
#define NSAMP    49          // linspace(0,1,50)[:-1] -> t_i = i/49
#define K2EXP    72.134752f  // 50/ln(2): sigmoid(50*(r-d)) = 1/(1+exp2(K2EXP*d - K2EXP*r))

#define NWAVES   16
#define PPW      (NPATHS / NWAVES)       // 64 paths per wave

// Per-path record (2x float4): [cx*K2EXP, cy*K2EXP, c2=-K2EXP*r, alpha | cr*a, cg*a, cb*a, pad]
// Coordinates pre-scaled by K2EXP so render computes exp2(sqrt(d2') + c2) with a
// plain v_add (no literal-in-VOP3 conflict, no extra fma). No cull: sigmoid
// saturates exactly (max arg ~ 102 -> 2^102 finite -> q=0, om=1).

__device__ __forceinline__ float sf(int v) { return __int_as_float(v); }

// One thread per (path, segment): 4096 threads in 64-thread blocks (spread
// across 64 CUs); 4-lane shfl_xor reduce per path.
__global__ __launch_bounds__(64) void path_setup_kernel(
    const float* __restrict__ cps,     // (P, 4, 4, 2)
    const float* __restrict__ colors,  // (P, 4)
    float* __restrict__ pd)            // (P, 8)
{
    const int tid = blockIdx.x * 64 + threadIdx.x;
    const int p = tid >> 2;
    const int s = tid & 3;

    const float4* cp4 = reinterpret_cast<const float4*>(cps);
    float4 a = cp4[p * 8 + s * 2];       // x0,y0,x1,y1
    float4 b = cp4[p * 8 + s * 2 + 1];   // x2,y2,x3,y3

    float sx = 0.0f, sy = 0.0f;
    for (int i = 0; i < NSAMP; ++i) {
        float t  = (float)i * (1.0f / 49.0f);
        float mt = 1.0f - t;
        float b0 = mt * mt * mt;
        float b1 = 3.0f * mt * mt * t;
        float b2 = 3.0f * mt * t * t;
        float b3 = t * t * t;
        sx += b0 * a.x + b1 * a.z + b2 * b.x + b3 * b.z;
        sy += b0 * a.y + b1 * a.w + b2 * b.y + b3 * b.w;
    }
    sx += __shfl_xor(sx, 1); sx += __shfl_xor(sx, 2);
    sy += __shfl_xor(sy, 1); sy += __shfl_xor(sy, 2);
    const float inv_n = 1.0f / 196.0f;
    float cx = sx * inv_n;
    float cy = sy * inv_n;

    float sr = 0.0f;
    for (int i = 0; i < NSAMP; ++i) {
        float t  = (float)i * (1.0f / 49.0f);
        float mt = 1.0f - t;
        float b0 = mt * mt * mt;
        float b1 = 3.0f * mt * mt * t;
        float b2 = 3.0f * mt * t * t;
        float b3 = t * t * t;
        float ptx = b0 * a.x + b1 * a.z + b2 * b.x + b3 * b.z;
        float pty = b0 * a.y + b1 * a.w + b2 * b.y + b3 * b.w;
        float dx = ptx - cx;
        float dy = pty - cy;
        sr += sqrtf(dx * dx + dy * dy);
    }
    sr += __shfl_xor(sr, 1); sr += __shfl_xor(sr, 2);
    float r = sr * inv_n;

    if (s == 0) {
        float4 col = reinterpret_cast<const float4*>(colors)[p];
        float4* o = reinterpret_cast<float4*>(pd) + (size_t)p * 2;
        o[0] = make_float4(cx * K2EXP, cy * K2EXP, -K2EXP * r, col.w);
        o[1] = make_float4(col.x * col.w, col.y * col.w, col.z * col.w, 0.0f);
    }
}

// One block = one 16x8 pixel tile, 1024 threads = 16 waves. Wave w composites
// paths [64w, 64w+64) for all 128 tile pixels (2 px/lane: 16x4 lane grid,
// sub-rows +0 and +4). Path table staged once in LDS; inner loop reads are
// broadcast ds_read_b128 with immediate offsets off one loop-uniform address
// (zero per-iter address math, zero bank conflicts, no SGPR-operand moves).
// Straight-line body, no exec churn. Ordered 16-map combine in LDS (reused).
__global__ __launch_bounds__(1024) void render_kernel(
    const float* __restrict__ pd,   // (P, 8)
    float* __restrict__ out)        // (3, H, W)
{
    __shared__ float4 lds[NPATHS * 2];   // 32 KB; reused as xch[16][2][64]

    // Stage path table: 2048 float4 / 1024 threads = 2 each, coalesced.
    {
        const float4* src = reinterpret_cast<const float4*>(pd);
        lds[threadIdx.x]        = src[threadIdx.x];
        lds[threadIdx.x + 1024] = src[threadIdx.x + 1024];
    }
    __syncthreads();

    const int wave = __builtin_amdgcn_readfirstlane((int)(threadIdx.x >> 6));
    const int lane = threadIdx.x & 63;
    const int lx = lane & 15;          // 0..15
    const int lq = lane >> 4;          // 0..3
    const int xx  = blockIdx.x * 16 + lx;    // 14 * 16 = 224
    const int yy0 = blockIdx.y * 8 + lq;     // 28 * 8  = 224
    const float pxs  = (float)xx * (K2EXP / 223.0f);          // pre-scaled coords
    const float py0s = (float)yy0 * (K2EXP / 223.0f);
    const float py1s = (float)(yy0 + 4) * (K2EXP / 223.0f);

    const float4* plds = lds + wave * (PPW * 2);   // wave-uniform LDS base

    float T0 = 1.0f, Ar0 = 0.0f, Ag0 = 0.0f, Ab0 = 0.0f;
    float T1 = 1.0f, Ar1 = 0.0f, Ag1 = 0.0f, Ab1 = 0.0f;

#pragma unroll 4
    for (int p = 0; p < PPW; ++p) {
        float4 d0 = plds[2 * p];       // cxs, cys, c2, alpha
        float4 d1 = plds[2 * p + 1];   // cr*a, cg*a, cb*a, pad
        float dx  = pxs - d0.x;
        float dy0 = py0s - d0.y;
        float dy1 = py1s - d0.y;
        float dx2 = dx * dx;
        float d20 = __builtin_fmaf(dy0, dy0, dx2);
        float d21 = __builtin_fmaf(dy1, dy1, dx2);
        float s0 = __builtin_amdgcn_sqrtf(d20);          // = K2EXP * dist0
        float s1 = __builtin_amdgcn_sqrtf(d21);
        float e0 = __builtin_amdgcn_exp2f(s0 + d0.z);    // plain v_add arg
        float e1 = __builtin_amdgcn_exp2f(s1 + d0.z);
        float q0 = __builtin_amdgcn_rcpf(1.0f + e0);     // sigmoid
        float q1 = __builtin_amdgcn_rcpf(1.0f + e1);
        float om0 = __builtin_fmaf(-d0.w, q0, 1.0f);     // 1 - alpha*q
        float om1 = __builtin_fmaf(-d0.w, q1, 1.0f);
        T0 *= om0;
        T1 *= om1;
        Ar0 = __builtin_fmaf(Ar0, om0, d1.x * q0);
        Ag0 = __builtin_fmaf(Ag0, om0, d1.y * q0);
        Ab0 = __builtin_fmaf(Ab0, om0, d1.z * q0);
        Ar1 = __builtin_fmaf(Ar1, om1, d1.x * q1);
        Ag1 = __builtin_fmaf(Ag1, om1, d1.y * q1);
        Ab1 = __builtin_fmaf(Ab1, om1, d1.z * q1);
    }

    // Ordered combine across the 16 waves; reuse staging LDS after barrier.
    __syncthreads();
    lds[wave * 128 + lane]      = make_float4(T0, Ar0, Ag0, Ab0);
    lds[wave * 128 + 64 + lane] = make_float4(T1, Ar1, Ag1, Ab1);
    __syncthreads();

    if (wave == 0) {
#pragma unroll
        for (int sub = 0; sub < 2; ++sub) {
            float R = 1.0f, G = 1.0f, Bb = 1.0f;
#pragma unroll
            for (int w = 0; w < NWAVES; ++w) {
                float4 c = lds[w * 128 + sub * 64 + lane];
                R  = __builtin_fmaf(R,  c.x, c.y);
                G  = __builtin_fmaf(G,  c.x, c.z);
                Bb = __builtin_fmaf(Bb, c.x, c.w);
            }
            const int pix = (yy0 + sub * 4) * CANVAS_W + xx;
            out[pix]            = R;
            out[NPIX + pix]     = G;
            out[2 * NPIX + pix] = Bb;
        }
    }
}

extern "C" void kernel_launch(void* const* d_in, const int* in_sizes, int n_in,
                              void* d_out, int out_size, void* d_ws, size_t ws_size,
                              hipStream_t stream) {
    const float* cps    = (const float*)d_in[0];
    const float* colors = (const float*)d_in[1];
    float* out = (float*)d_out;
    float* pd  = (float*)d_ws;   // 32 KB

    path_setup_kernel<<<(NPATHS * 4) / 64, 64, 0, stream>>>(cps, colors, pd);

    dim3 grid(CANVAS_W / 16, CANVAS_H / 8);   // 14 x 28 = 392 blocks
    render_kernel<<<grid, 1024, 0, stream>>>(pd, out);
}